// Round 23
// baseline (43.935 us; speedup 1.0000x reference)
//
#include <hip/hip_runtime.h>

#define IMG   224
#define IMG2  (IMG*IMG)
#define NN    27          // patches per dim
#define KK    256         // pixels per patch
#define EE    128
#define SCOLS 232         // ring row stride in elems (464 B)
#define RSTR  136         // rec row stride in elems (272 B, b128-aligned)

typedef float f32x4 __attribute__((ext_vector_type(4)));
typedef short s16x8 __attribute__((ext_vector_type(8)));
typedef short s16x4 __attribute__((ext_vector_type(4)));

__device__ __forceinline__ unsigned short f2bf(float f) {
    unsigned int u = __float_as_uint(f);
    u = (u + 0x7fffu + ((u >> 16) & 1u)) >> 16;   // RNE (inputs finite)
    return (unsigned short)u;
}
__device__ __forceinline__ float bf2f(unsigned short u) {
    return __uint_as_float((unsigned int)u << 16);
}
// register-only packed cvt (RNE); single-instruction asm, no early-clobber hazard
__device__ __forceinline__ uint2 pack4(f32x4 r) {
    uint2 u;
    asm("v_cvt_pk_bf16_f32 %0, %1, %2" : "=v"(u.x) : "v"(r.x), "v"(r.y));
    asm("v_cvt_pk_bf16_f32 %0, %1, %2" : "=v"(u.y) : "v"(r.z), "v"(r.w));
    return u;
}

// KPB=4: each block computes 4 k-rows per full W_enc stream (quarters L2 traffic
// vs KPB=1; ~25 MB total). v computed via four 64-wide (single-wave) reductions.
__global__ void pack_M(const float* __restrict__ W_enc, const float* __restrict__ W_dec,
                       const float* __restrict__ b_enc, const float* __restrict__ b_dec,
                       unsigned short* __restrict__ APK, float* __restrict__ v) {
    const int k0 = blockIdx.x*4, c = blockIdx.y, j = threadIdx.x;
    const float* wd = W_dec + ((size_t)c*KK + k0)*EE;   // 4 consecutive k rows
    const float* we = W_enc + (size_t)c*EE*KK + j;
    float a0 = 0.f, a1 = 0.f, a2 = 0.f, a3 = 0.f;
    #pragma unroll 4
    for (int e = 0; e < EE; ++e) {
        float wv = we[(size_t)e*KK];
        a0 = fmaf(wd[e],        wv, a0);
        a1 = fmaf(wd[EE + e],   wv, a1);
        a2 = fmaf(wd[2*EE + e], wv, a2);
        a3 = fmaf(wd[3*EE + e], wv, a3);
    }
    const int jb = j >> 5, g = (j >> 3) & 3, i = j & 7;
    {
        const size_t base = (size_t)c*65536 + (size_t)(jb*64 + g*16)*8 + i;
        int k = k0, kf, kr;
        kf = k >> 4; kr = k & 15; APK[base + ((size_t)kf*8*64 + kr)*8] = f2bf(a0);
        k = k0+1; kf = k >> 4; kr = k & 15; APK[base + ((size_t)kf*8*64 + kr)*8] = f2bf(a1);
        k = k0+2; kf = k >> 4; kr = k & 15; APK[base + ((size_t)kf*8*64 + kr)*8] = f2bf(a2);
        k = k0+3; kf = k >> 4; kr = k & 15; APK[base + ((size_t)kf*8*64 + kr)*8] = f2bf(a3);
    }

    // v[c][k0+kt] = b_dec + sum_e wd[kt][e]*be[e]; kt = wave id (64-thread groups)
    __shared__ float pv[256];
    const float* be = b_enc + c*EE;
    const int kt = j >> 6, e0 = j & 63;
    const float* wdk = wd + (size_t)kt*EE;
    pv[j] = wdk[e0]*be[e0] + wdk[e0 + 64]*be[e0 + 64];
    __syncthreads();
    for (int off = 32; off > 0; off >>= 1) {
        if (e0 < off) pv[j] += pv[j + off];
        __syncthreads();
    }
    if (e0 == 0) v[c*KK + k0 + kt] = pv[j] + b_dec[c*KK + k0 + kt];
}

// Block = (b, c, quarter q): strips 7q..7q+6 in a loop. 8 waves = 2 prow x 4 kq;
// 16 A frags (64 VGPR) asm-pinned once per block. Single barrier per iteration:
// rec double-buffered by strip parity; epilogue for strip s-1 runs inside iter s.
__global__ __launch_bounds__(512, 4)
void patch_ae_loop(const float* __restrict__ x, const unsigned short* __restrict__ APK,
                   const float* __restrict__ v, float* __restrict__ out) {
    // bijective XCD swizzle: 768 blocks = 8 XCDs x 96
    const int hid = blockIdx.x;
    const int lid = (hid & 7)*96 + (hid >> 3);
    const int q   = lid & 3;
    const int t2  = lid >> 2;       // 0..191
    const int c   = t2 % 3;
    const int b   = t2 / 3;
    const int s0  = 7*q;

    const int tid  = threadIdx.x;
    const int lane = tid & 63, wave = tid >> 6;

    __shared__ __align__(16) unsigned short ring[32*SCOLS];       // 14848 B (4 groups x 8 rows)
    // rec[parity][prow]: slots 0=zero, 1..27=patches 0..26, 28=zero, 29=dump
    __shared__ __align__(16) unsigned short rec[2][2][30][RSTR];  // 32640 B
    __shared__ __align__(16) float vsh[256];                      // 1024 B

    if (tid < 256) vsh[tid] = v[c*256 + tid];
    if (tid < RSTR) {   // zero rows (slots 0 and 28, both parities, both prows)
        rec[0][0][0][tid] = 0; rec[0][0][28][tid] = 0;
        rec[0][1][0][tid] = 0; rec[0][1][28][tid] = 0;
        rec[1][0][0][tid] = 0; rec[1][0][28][tid] = 0;
        rec[1][1][0][tid] = 0; rec[1][1][28][tid] = 0;
    }

    // wave constants: 8 waves = 2 prow x 4 kq (32 k-rows each)
    const int prow   = wave >> 2;      // 0: ny=s, 1: ny=s-1
    const int kq     = wave & 3;
    const int kfbase = prow*8 + kq*2;
    const int g = lane >> 4, lr = lane & 15;
    const int jx0 = (g & 1)*8;
    const int c1 = (lr <= 10) ? (128 + 8*lr) : 208;   // pf1 col, clamped (p>=27 unused)
    const int rowoff = prow ? -8 : 0;

    // ---- A: 16 frags loaded ONCE, asm-pinned (13-bit signed imm: offsets < 4096) ----
    const int kfu = __builtin_amdgcn_readfirstlane(kfbase);
    const char* abase = (const char*)(APK + (size_t)c*65536) + (size_t)kfu*8192;
    const int v0a = lane*16,       v0b = v0a + 4096;
    const int v1a = v0a + 8192,    v1b = v0a + 12288;

#define ALD(VAR, VOFF, OFFSTR)                                      \
    asm volatile("global_load_dwordx4 %0, %1, %2 offset:" OFFSTR    \
                 : "=v"(VAR) : "v"(VOFF), "s"(abase));

    s16x8 a0_0,a0_1,a0_2,a0_3,a0_4,a0_5,a0_6,a0_7;
    s16x8 a1_0,a1_1,a1_2,a1_3,a1_4,a1_5,a1_6,a1_7;
    ALD(a0_0, v0a, "0")  ALD(a0_1, v0a, "1024") ALD(a0_2, v0a, "2048") ALD(a0_3, v0a, "3072")
    ALD(a0_4, v0b, "0")  ALD(a0_5, v0b, "1024") ALD(a0_6, v0b, "2048") ALD(a0_7, v0b, "3072")
    ALD(a1_0, v1a, "0")  ALD(a1_1, v1a, "1024") ALD(a1_2, v1a, "2048") ALD(a1_3, v1a, "3072")
    ALD(a1_4, v1b, "0")  ALD(a1_5, v1b, "1024") ALD(a1_6, v1b, "2048") ALD(a1_7, v1b, "3072")
#undef ALD

    const float* xb = x + (size_t)(b*3 + c)*IMG2;

    // ---- prologue staging: groups s0-1, s0, s0+1 (24 rows, row-clamped) ----
    #pragma unroll
    for (int it = 0; it < 2; ++it) {
        int ci = tid + it*512;
        if (ci < 672) {
            int r  = ci / 28, cc = ci - (ci/28)*28;
            int ar = 8*s0 - 8 + r;                 // absolute image row (may be OOB)
            int yr = ar < 0 ? 0 : (ar > 223 ? 223 : ar);
            const float4* src = (const float4*)(xb + (size_t)yr*IMG + cc*8);
            float4 lo = src[0], hi = src[1];
            uint2 u0 = pack4((f32x4){lo.x, lo.y, lo.z, lo.w});
            uint2 u1 = pack4((f32x4){hi.x, hi.y, hi.z, hi.w});
            *((uint4*)&ring[(ar & 31)*SCOLS + cc*8]) = make_uint4(u0.x, u0.y, u1.x, u1.y);
        }
    }
    __syncthreads();
    asm volatile("s_waitcnt vmcnt(0)");     // A frags resident before first MFMA
    __builtin_amdgcn_sched_barrier(0);

    // per-strip staging constants (tid<448: one 4-px chunk of the 8-row group)
    const int sr  = tid / 56;
    const int sc4 = tid - 56*(tid/56);

    // epilogue constants (tid<448: 4 output px)
    const int em   = tid % 56, ery = tid / 56;
    const int eq   = em >> 1, ehh = em & 1;
    const int ev1  = (eq < 27), ev0 = (eq > 0);
    const int kl1  = ery*16 + 4*ehh;
    const int kl0  = kl1 + 8;

#define EPILOGUE(ES)                                                                     \
        if (tid < 448) {                                                                 \
            const int par = (ES) & 1;                                                    \
            const int h0 = ((ES) < 27);                                                  \
            const int h1 = ((ES) > 0);                                                   \
            const int shift = (ev0 & ev1) + (h0 & h1);                                   \
            const float inv = __int_as_float(0x3f800000 - (shift << 23));                \
            float sum[4];                                                                \
            _Pragma("unroll")                                                            \
            for (int d = 0; d < 4; ++d) sum[d] = 0.f;                                    \
            if (h0) {                                                                    \
                s16x4 rrv = *((const s16x4*)&rec[par][0][eq+1][kl1]);                    \
                s16x4 llv = *((const s16x4*)&rec[par][0][eq][kl0]);                      \
                _Pragma("unroll")                                                        \
                for (int d = 0; d < 4; ++d)                                              \
                    sum[d] += bf2f((unsigned short)rrv[d]) + bf2f((unsigned short)llv[d]); \
            }                                                                            \
            if (h1) {                                                                    \
                s16x4 rrv = *((const s16x4*)&rec[par][1][eq+1][kl1]);                    \
                s16x4 llv = *((const s16x4*)&rec[par][1][eq][kl0]);                      \
                _Pragma("unroll")                                                        \
                for (int d = 0; d < 4; ++d)                                              \
                    sum[d] += bf2f((unsigned short)rrv[d]) + bf2f((unsigned short)llv[d]); \
            }                                                                            \
            float* orow = out + (size_t)(b*3 + c)*IMG2 + (size_t)(8*(ES) + ery)*IMG + 4*em; \
            f32x4 o = {sum[0]*inv, sum[1]*inv, sum[2]*inv, sum[3]*inv};                  \
            *((f32x4*)orow) = o;                                                         \
        }

#define MFMA2(AF, B0, B1, F)                                                             \
        acc[F][0] = __builtin_amdgcn_mfma_f32_16x16x32_bf16(AF, B0, acc[F][0], 0, 0, 0); \
        acc[F][1] = __builtin_amdgcn_mfma_f32_16x16x32_bf16(AF, B1, acc[F][1], 0, 0, 0);

#define MSTEP(JB, A0, A1)                                                            \
        {                                                                            \
            const int jy = 2*(JB) + (g >> 1);                                        \
            const unsigned short* srow = &ring[((rowb + jy) & 31)*SCOLS + jx0];      \
            s16x8 bf0 = *((const s16x8*)&srow[8*lr]);                                \
            s16x8 bf1 = *((const s16x8*)&srow[c1]);                                  \
            __builtin_amdgcn_s_setprio(1);                                           \
            MFMA2(A0, bf0, bf1, 0) MFMA2(A1, bf0, bf1, 1)                            \
            __builtin_amdgcn_s_setprio(0);                                           \
        }

    #pragma unroll 1
    for (int s = s0; s < s0 + 7; ++s) {
        // 1. issue prefetch of group s+2 (8 rows; 448 threads x 16B)
        f32x4 ga0;
        if (tid < 448) {
            int yr = 8*(s+2) + sr; if (yr > 223) yr = 223;   // clamp: garbage rows unread
            int voffx = yr*(IMG*4) + sc4*16;
            asm volatile("global_load_dwordx4 %0, %1, %2" : "=v"(ga0) : "v"(voffx), "s"(xb));
        }

        // 2. MFMA over strip s (A pinned in regs, B from ring)
        f32x4 acc[2][2];
        #pragma unroll
        for (int f = 0; f < 2; ++f)
            #pragma unroll
            for (int pf = 0; pf < 2; ++pf)
                acc[f][pf] = (f32x4){0.f, 0.f, 0.f, 0.f};
        const int rowb = 8*s + rowoff;
        MSTEP(0, a0_0, a1_0)
        MSTEP(1, a0_1, a1_1)
        MSTEP(2, a0_2, a1_2)
        MSTEP(3, a0_3, a1_3)
        MSTEP(4, a0_4, a1_4)
        MSTEP(5, a0_5, a1_5)
        MSTEP(6, a0_6, a1_6)
        MSTEP(7, a0_7, a1_7)

        // 3. bias + bf16 rec store into parity buffer s&1
        {
            const int par = s & 1;
            #pragma unroll
            for (int f = 0; f < 2; ++f) {
                int klocal = kq*32 + f*16 + g*4;
                f32x4 bias = *((const f32x4*)&vsh[prow*128 + klocal]);
                #pragma unroll
                for (int pf = 0; pf < 2; ++pf) {
                    f32x4 r = acc[f][pf] + bias;
                    int pidx = pf*16 + lr + 1;
                    if (pidx >= 28) pidx = 29;
                    *((uint2*)&rec[par][prow][pidx][klocal]) = pack4(r);
                }
            }
        }

        // 4. deferred epilogue for strip s-1 (rec[(s-1)&1] stable: written pre-previous barrier)
        if (s > s0) { EPILOGUE(s-1) }

        // 5. ring write of prefetched group s+2 (slot (s+2)%4 disjoint from read slots)
        if (tid < 448) {
            asm volatile("s_waitcnt vmcnt(0)");
            __builtin_amdgcn_sched_barrier(0);
            uint2 u0 = pack4(ga0);
            int ar2 = 8*(s+2) + sr;
            *((uint2*)&ring[(ar2 & 31)*SCOLS + sc4*4]) = u0;
        }

        __syncthreads();   // single barrier: rec(s) ready for epi(s) @iter s+1; ring ready
    }

    // tail: epilogue for the last strip (rec written pre-final-barrier)
    EPILOGUE(s0 + 6)
#undef MSTEP
#undef MFMA2
#undef EPILOGUE
}

extern "C" void kernel_launch(void* const* d_in, const int* in_sizes, int n_in,
                              void* d_out, int out_size, void* d_ws, size_t ws_size,
                              hipStream_t stream) {
    (void)in_sizes; (void)n_in; (void)out_size; (void)ws_size;
    const float* x     = (const float*)d_in[0];
    const float* W_enc = (const float*)d_in[1];
    const float* b_enc = (const float*)d_in[2];
    const float* W_dec = (const float*)d_in[3];
    const float* b_dec = (const float*)d_in[4];
    float* out = (float*)d_out;

    float*          v   = (float*)d_ws;                          // 768 f32
    unsigned short* APK = (unsigned short*)((char*)d_ws + 4096); // 3 x 65536 bf16 = 384 KB

    pack_M<<<dim3(KK/4, 3), 256, 0, stream>>>(W_enc, W_dec, b_enc, b_dec, APK, v);
    patch_ae_loop<<<dim3(768), 512, 0, stream>>>(x, APK, v, out);
}

// Round 24
// 40.124 us; speedup vs baseline: 1.0950x; 1.0950x over previous
//
#include <hip/hip_runtime.h>

#define IMG   224
#define IMG2  (IMG*IMG)
#define NN    27          // patches per dim
#define KK    256         // pixels per patch
#define EE    128
#define SCOLS 232         // ring row stride in elems (464 B)
#define RSTR  136         // rec row stride in elems (272 B, b128-aligned)

typedef float f32x4 __attribute__((ext_vector_type(4)));
typedef short s16x8 __attribute__((ext_vector_type(8)));
typedef short s16x4 __attribute__((ext_vector_type(4)));

__device__ __forceinline__ unsigned short f2bf(float f) {
    unsigned int u = __float_as_uint(f);
    u = (u + 0x7fffu + ((u >> 16) & 1u)) >> 16;   // RNE (inputs finite)
    return (unsigned short)u;
}
__device__ __forceinline__ float bf2f(unsigned short u) {
    return __uint_as_float((unsigned int)u << 16);
}
// register-only packed cvt (RNE); single-instruction asm, no early-clobber hazard
__device__ __forceinline__ uint2 pack4(f32x4 r) {
    uint2 u;
    asm("v_cvt_pk_bf16_f32 %0, %1, %2" : "=v"(u.x) : "v"(r.x), "v"(r.y));
    asm("v_cvt_pk_bf16_f32 %0, %1, %2" : "=v"(u.y) : "v"(r.z), "v"(r.w));
    return u;
}

// KPB=2: each block computes 2 k-rows per full W_enc stream (halves L2 traffic).
__global__ void pack_M(const float* __restrict__ W_enc, const float* __restrict__ W_dec,
                       const float* __restrict__ b_enc, const float* __restrict__ b_dec,
                       unsigned short* __restrict__ APK, float* __restrict__ v) {
    const int k0 = blockIdx.x*2, c = blockIdx.y, j = threadIdx.x;
    const float* wd0 = W_dec + ((size_t)c*KK + k0)*EE;
    const float* wd1 = wd0 + EE;
    const float* we  = W_enc + (size_t)c*EE*KK + j;
    float a0 = 0.f, a1 = 0.f;
    #pragma unroll 8
    for (int e = 0; e < EE; ++e) {
        float wv = we[(size_t)e*KK];
        a0 = fmaf(wd0[e], wv, a0);
        a1 = fmaf(wd1[e], wv, a1);
    }
    const int jb = j >> 5, g = (j >> 3) & 3, i = j & 7;
    {
        int kf = k0 >> 4, kr = k0 & 15;
        APK[(size_t)c*65536 + (((kf*8 + jb)*64) + g*16 + kr)*8 + i] = f2bf(a0);
        kf = (k0+1) >> 4; kr = (k0+1) & 15;
        APK[(size_t)c*65536 + (((kf*8 + jb)*64) + g*16 + kr)*8 + i] = f2bf(a1);
    }

    __shared__ float pv[256];
    const float* be = b_enc + c*EE;
    pv[j] = (j < EE) ? wd0[j]*be[j] : wd1[j-EE]*be[j-EE];
    __syncthreads();
    for (int off = 64; off > 0; off >>= 1) {
        if ((j & 127) < off) pv[j] += pv[j + off];
        __syncthreads();
    }
    if (j == 0)   v[c*KK + k0]     = pv[0]   + b_dec[c*KK + k0];
    if (j == 128) v[c*KK + k0 + 1] = pv[128] + b_dec[c*KK + k0 + 1];
}

// Block = (b, c, quarter q): strips 7q..7q+6 in a loop. 8 waves = 2 prow x 4 kq;
// 16 A frags (64 VGPR) asm-pinned once per block. Single barrier per iteration:
// rec double-buffered by strip parity; epilogue for strip s-1 runs inside iter s.
__global__ __launch_bounds__(512, 4)
void patch_ae_loop(const float* __restrict__ x, const unsigned short* __restrict__ APK,
                   const float* __restrict__ v, float* __restrict__ out) {
    // bijective XCD swizzle: 768 blocks = 8 XCDs x 96
    const int hid = blockIdx.x;
    const int lid = (hid & 7)*96 + (hid >> 3);
    const int q   = lid & 3;
    const int t2  = lid >> 2;       // 0..191
    const int c   = t2 % 3;
    const int b   = t2 / 3;
    const int s0  = 7*q;

    const int tid  = threadIdx.x;
    const int lane = tid & 63, wave = tid >> 6;

    __shared__ __align__(16) unsigned short ring[32*SCOLS];       // 14848 B (4 groups x 8 rows)
    // rec[parity][prow]: slots 0=zero, 1..27=patches 0..26, 28=zero, 29=dump
    __shared__ __align__(16) unsigned short rec[2][2][30][RSTR];  // 32640 B
    __shared__ __align__(16) float vsh[256];                      // 1024 B

    if (tid < 256) vsh[tid] = v[c*256 + tid];
    if (tid < RSTR) {   // zero rows (slots 0 and 28, both parities, both prows)
        rec[0][0][0][tid] = 0; rec[0][0][28][tid] = 0;
        rec[0][1][0][tid] = 0; rec[0][1][28][tid] = 0;
        rec[1][0][0][tid] = 0; rec[1][0][28][tid] = 0;
        rec[1][1][0][tid] = 0; rec[1][1][28][tid] = 0;
    }

    // wave constants: 8 waves = 2 prow x 4 kq (32 k-rows each)
    const int prow   = wave >> 2;      // 0: ny=s, 1: ny=s-1
    const int kq     = wave & 3;
    const int kfbase = prow*8 + kq*2;
    const int g = lane >> 4, lr = lane & 15;
    const int jx0 = (g & 1)*8;
    const int c1 = (lr <= 10) ? (128 + 8*lr) : 208;   // pf1 col, clamped (p>=27 unused)
    const int rowoff = prow ? -8 : 0;

    // ---- A: 16 frags loaded ONCE, asm-pinned (13-bit signed imm: offsets < 4096) ----
    const int kfu = __builtin_amdgcn_readfirstlane(kfbase);
    const char* abase = (const char*)(APK + (size_t)c*65536) + (size_t)kfu*8192;
    const int v0a = lane*16,       v0b = v0a + 4096;
    const int v1a = v0a + 8192,    v1b = v0a + 12288;

#define ALD(VAR, VOFF, OFFSTR)                                      \
    asm volatile("global_load_dwordx4 %0, %1, %2 offset:" OFFSTR    \
                 : "=v"(VAR) : "v"(VOFF), "s"(abase));

    s16x8 a0_0,a0_1,a0_2,a0_3,a0_4,a0_5,a0_6,a0_7;
    s16x8 a1_0,a1_1,a1_2,a1_3,a1_4,a1_5,a1_6,a1_7;
    ALD(a0_0, v0a, "0")  ALD(a0_1, v0a, "1024") ALD(a0_2, v0a, "2048") ALD(a0_3, v0a, "3072")
    ALD(a0_4, v0b, "0")  ALD(a0_5, v0b, "1024") ALD(a0_6, v0b, "2048") ALD(a0_7, v0b, "3072")
    ALD(a1_0, v1a, "0")  ALD(a1_1, v1a, "1024") ALD(a1_2, v1a, "2048") ALD(a1_3, v1a, "3072")
    ALD(a1_4, v1b, "0")  ALD(a1_5, v1b, "1024") ALD(a1_6, v1b, "2048") ALD(a1_7, v1b, "3072")
#undef ALD

    const float* xb = x + (size_t)(b*3 + c)*IMG2;

    // ---- prologue staging: groups s0-1, s0, s0+1 (24 rows, row-clamped) ----
    #pragma unroll
    for (int it = 0; it < 2; ++it) {
        int ci = tid + it*512;
        if (ci < 672) {
            int r  = ci / 28, cc = ci - (ci/28)*28;
            int ar = 8*s0 - 8 + r;                 // absolute image row (may be OOB)
            int yr = ar < 0 ? 0 : (ar > 223 ? 223 : ar);
            const float4* src = (const float4*)(xb + (size_t)yr*IMG + cc*8);
            float4 lo = src[0], hi = src[1];
            uint2 u0 = pack4((f32x4){lo.x, lo.y, lo.z, lo.w});
            uint2 u1 = pack4((f32x4){hi.x, hi.y, hi.z, hi.w});
            *((uint4*)&ring[(ar & 31)*SCOLS + cc*8]) = make_uint4(u0.x, u0.y, u1.x, u1.y);
        }
    }
    __syncthreads();
    asm volatile("s_waitcnt vmcnt(0)");     // A frags resident before first MFMA
    __builtin_amdgcn_sched_barrier(0);

    // per-strip staging constants (tid<448: one 4-px chunk of the 8-row group)
    const int sr  = tid / 56;
    const int sc4 = tid - 56*(tid/56);

    // epilogue constants (tid<448: 4 output px)
    const int em   = tid % 56, ery = tid / 56;
    const int eq   = em >> 1, ehh = em & 1;
    const int ev1  = (eq < 27), ev0 = (eq > 0);
    const int kl1  = ery*16 + 4*ehh;
    const int kl0  = kl1 + 8;

#define EPILOGUE(ES)                                                                     \
        if (tid < 448) {                                                                 \
            const int par = (ES) & 1;                                                    \
            const int h0 = ((ES) < 27);                                                  \
            const int h1 = ((ES) > 0);                                                   \
            const int shift = (ev0 & ev1) + (h0 & h1);                                   \
            const float inv = __int_as_float(0x3f800000 - (shift << 23));                \
            float sum[4];                                                                \
            _Pragma("unroll")                                                            \
            for (int d = 0; d < 4; ++d) sum[d] = 0.f;                                    \
            if (h0) {                                                                    \
                s16x4 rrv = *((const s16x4*)&rec[par][0][eq+1][kl1]);                    \
                s16x4 llv = *((const s16x4*)&rec[par][0][eq][kl0]);                      \
                _Pragma("unroll")                                                        \
                for (int d = 0; d < 4; ++d)                                              \
                    sum[d] += bf2f((unsigned short)rrv[d]) + bf2f((unsigned short)llv[d]); \
            }                                                                            \
            if (h1) {                                                                    \
                s16x4 rrv = *((const s16x4*)&rec[par][1][eq+1][kl1]);                    \
                s16x4 llv = *((const s16x4*)&rec[par][1][eq][kl0]);                      \
                _Pragma("unroll")                                                        \
                for (int d = 0; d < 4; ++d)                                              \
                    sum[d] += bf2f((unsigned short)rrv[d]) + bf2f((unsigned short)llv[d]); \
            }                                                                            \
            float* orow = out + (size_t)(b*3 + c)*IMG2 + (size_t)(8*(ES) + ery)*IMG + 4*em; \
            f32x4 o = {sum[0]*inv, sum[1]*inv, sum[2]*inv, sum[3]*inv};                  \
            *((f32x4*)orow) = o;                                                         \
        }

#define MFMA2(AF, B0, B1, F)                                                             \
        acc[F][0] = __builtin_amdgcn_mfma_f32_16x16x32_bf16(AF, B0, acc[F][0], 0, 0, 0); \
        acc[F][1] = __builtin_amdgcn_mfma_f32_16x16x32_bf16(AF, B1, acc[F][1], 0, 0, 0);

#define MSTEP(JB, A0, A1)                                                            \
        {                                                                            \
            const int jy = 2*(JB) + (g >> 1);                                        \
            const unsigned short* srow = &ring[((rowb + jy) & 31)*SCOLS + jx0];      \
            s16x8 bf0 = *((const s16x8*)&srow[8*lr]);                                \
            s16x8 bf1 = *((const s16x8*)&srow[c1]);                                  \
            __builtin_amdgcn_s_setprio(1);                                           \
            MFMA2(A0, bf0, bf1, 0) MFMA2(A1, bf0, bf1, 1)                            \
            __builtin_amdgcn_s_setprio(0);                                           \
        }

    #pragma unroll 1
    for (int s = s0; s < s0 + 7; ++s) {
        // 1. issue prefetch of group s+2 (8 rows; 448 threads x 16B)
        f32x4 ga0;
        if (tid < 448) {
            int yr = 8*(s+2) + sr; if (yr > 223) yr = 223;   // clamp: garbage rows unread
            int voffx = yr*(IMG*4) + sc4*16;
            asm volatile("global_load_dwordx4 %0, %1, %2" : "=v"(ga0) : "v"(voffx), "s"(xb));
        }

        // 2. MFMA over strip s (A pinned in regs, B from ring)
        f32x4 acc[2][2];
        #pragma unroll
        for (int f = 0; f < 2; ++f)
            #pragma unroll
            for (int pf = 0; pf < 2; ++pf)
                acc[f][pf] = (f32x4){0.f, 0.f, 0.f, 0.f};
        const int rowb = 8*s + rowoff;
        MSTEP(0, a0_0, a1_0)
        MSTEP(1, a0_1, a1_1)
        MSTEP(2, a0_2, a1_2)
        MSTEP(3, a0_3, a1_3)
        MSTEP(4, a0_4, a1_4)
        MSTEP(5, a0_5, a1_5)
        MSTEP(6, a0_6, a1_6)
        MSTEP(7, a0_7, a1_7)

        // 3. bias + bf16 rec store into parity buffer s&1
        {
            const int par = s & 1;
            #pragma unroll
            for (int f = 0; f < 2; ++f) {
                int klocal = kq*32 + f*16 + g*4;
                f32x4 bias = *((const f32x4*)&vsh[prow*128 + klocal]);
                #pragma unroll
                for (int pf = 0; pf < 2; ++pf) {
                    f32x4 r = acc[f][pf] + bias;
                    int pidx = pf*16 + lr + 1;
                    if (pidx >= 28) pidx = 29;
                    *((uint2*)&rec[par][prow][pidx][klocal]) = pack4(r);
                }
            }
        }

        // 4. deferred epilogue for strip s-1 (rec[(s-1)&1] stable: written pre-previous barrier)
        if (s > s0) { EPILOGUE(s-1) }

        // 5. ring write of prefetched group s+2 (slot (s+2)%4 disjoint from read slots)
        if (tid < 448) {
            asm volatile("s_waitcnt vmcnt(0)");
            __builtin_amdgcn_sched_barrier(0);
            uint2 u0 = pack4(ga0);
            int ar2 = 8*(s+2) + sr;
            *((uint2*)&ring[(ar2 & 31)*SCOLS + sc4*4]) = u0;
        }

        __syncthreads();   // single barrier: rec(s) ready for epi(s) @iter s+1; ring ready
    }

    // tail: epilogue for the last strip (rec written pre-final-barrier)
    EPILOGUE(s0 + 6)
#undef MSTEP
#undef MFMA2
#undef EPILOGUE
}

extern "C" void kernel_launch(void* const* d_in, const int* in_sizes, int n_in,
                              void* d_out, int out_size, void* d_ws, size_t ws_size,
                              hipStream_t stream) {
    (void)in_sizes; (void)n_in; (void)out_size; (void)ws_size;
    const float* x     = (const float*)d_in[0];
    const float* W_enc = (const float*)d_in[1];
    const float* b_enc = (const float*)d_in[2];
    const float* W_dec = (const float*)d_in[3];
    const float* b_dec = (const float*)d_in[4];
    float* out = (float*)d_out;

    float*          v   = (float*)d_ws;                          // 768 f32
    unsigned short* APK = (unsigned short*)((char*)d_ws + 4096); // 3 x 65536 bf16 = 384 KB

    pack_M<<<dim3(KK/2, 3), 256, 0, stream>>>(W_enc, W_dec, b_enc, b_dec, APK, v);
    patch_ae_loop<<<dim3(768), 512, 0, stream>>>(x, APK, v, out);
}